// Round 4
// baseline (251.785 us; speedup 1.0000x reference)
//
#include <hip/hip_runtime.h>
#include <math.h>

#pragma clang fp contract(off)

// Problem constants (match reference)
#define PNUM 136500      // sum of f*f
#define HPNUM 68250      // PNUM/2 (exact)
#define BNUM 16
#define TOPK 5000
#define CAP 8192         // candidate capacity per image
#define NB2 1024         // histogram window buckets (covers ord16 of (0.01, 1.0))
#define B2BASE 0xBC00u   // window base: f2ord(0.01)>>16 = 0xBC23 >= 0xBC00
#define NWORDS 79        // ceil(5000/64)
#define NW32 158         // 32-bit state words per image (NWORDS*2)
#define GSTRIDE 32       // ecnt padding: 32 u32 = 128 B per image
#define CAPE 65536       // edge capacity per image (expected E ~ 1-3k)
#define ELDS 10240       // LDS edge-copy capacity (global fallback beyond)
#define NXB 128          // spatial x1 buckets
#define BSTRIDE 5120     // per-image bucket-array stride (>= TOPK)
#define EBUF 3072        // per-block LDS edge buffer
#define NHB 16           // k_hist blocks per image (= partial slices)

// Workspace layout (bytes).
#define OFF_SC    ((size_t)0)                 // 320,000
#define OFF_BOX4  (OFF_SC + 320000)           // 16*5000*16 = 1,280,000
#define OFF_HIST  ((size_t)1920000)           // summed hist: 16*1024*4 = 65,536
#define OFF_CUT   (OFF_HIST + 65536)          // 64
#define OFF_SBASE (OFF_CUT + 64)              // 65,536
#define OFF_GBCUR (OFF_SBASE + 65536)         // 1,048,576: k_hist partials, then
                                              // zeroed in k_cutoff2 -> gbcur
#define OFF_KEYS  (OFF_GBCUR + 1048576)       // 16*8192*8 = 1,048,576
#define OFF_ECNT  (OFF_KEYS + 1048576)        // 2,048
#define OFF_BCNT  (OFF_ECNT + 2048)           // 16*128*4 = 8,192
#define OFF_BCUR  (OFF_BCNT + 8192)           // 8,192
#define OFF_EDGE  (OFF_BCUR + 8192)           // 16*65536*4 = 4,194,304
#define OFF_GRP   (OFF_EDGE + 4194304)        // overlay region for bucket arrays
#define OFF_BOFS  (OFF_GRP)                   // 16*130*4 (pad to 16384)
#define OFF_SIDX  (OFF_GRP + 16384)           // u32 [16*5120]
#define OFF_SBOX  (OFF_SIDX + 327680)         // float4 [16*5120] = 1,310,720

__device__ __forceinline__ unsigned f2ord(float f) {
    unsigned u = __float_as_uint(f);
    return (u & 0x80000000u) ? ~u : (u | 0x80000000u);
}
__device__ __forceinline__ float ord2f(unsigned o) {
    unsigned u = (o & 0x80000000u) ? (o ^ 0x80000000u) : ~o;
    return __uint_as_float(u);
}
// monotone x1 -> bucket map; identical in k_decode, k_bscat, k_pair4
__device__ __forceinline__ int bucketOf(float x) {
    int b = (int)((x + 0.6f) * 71.111115f);   // 128 buckets over [-0.6, 1.2]
    return (b < 0) ? 0 : ((b > 127) ? 127 : b);
}

// K1: per-image LDS histogram; each block stores its PARTIAL slice (no
// pre-zero of global memory, no atomic merge). parts[img][blk][1024].
__global__ void __launch_bounds__(256) k_hist(const float* __restrict__ conf,
                                              unsigned* __restrict__ parts) {
    __shared__ unsigned lh[NB2];
    int img = blockIdx.y;
    for (int i = threadIdx.x; i < NB2; i += 256) lh[i] = 0;
    __syncthreads();
    const float4* src = (const float4*)(conf + (size_t)img * PNUM * 2);
    int stride = gridDim.x * 256;
    for (int q = blockIdx.x * 256 + threadIdx.x; q < HPNUM; q += stride) {
        float4 v = src[q];
        if (v.y > 0.01f) atomicAdd(&lh[(f2ord(v.y) >> 16) - B2BASE], 1u);
        if (v.w > 0.01f) atomicAdd(&lh[(f2ord(v.w) >> 16) - B2BASE], 1u);
    }
    __syncthreads();
    unsigned* p = parts + ((size_t)img * NHB + blockIdx.x) * NB2;
    for (int i = threadIdx.x; i < NB2; i += 256) p[i] = lh[i];
}

// K2: reduce partials -> summed hist, cutoff + per-bucket suffix base ranks.
// Also zeroes gbcur (overlaid on parts, post-read), ecnt, bcnt, bcur --
// replaces the workspace memset node entirely.
__global__ void __launch_bounds__(256) k_cutoff2(
        unsigned* __restrict__ parts,          // == gbcur region
        unsigned* __restrict__ shist, unsigned* __restrict__ cut,
        unsigned* __restrict__ sbase, unsigned* __restrict__ ecnt,
        unsigned* __restrict__ bcnt, unsigned* __restrict__ bcur) {
    __shared__ unsigned csum[256], suf[256];
    int img = blockIdx.x;
    int t = threadIdx.x;
    const unsigned* pp = parts + (size_t)img * NHB * NB2;
    unsigned h0 = 0, h1 = 0, h2 = 0, h3 = 0;
    #pragma unroll
    for (int blk = 0; blk < NHB; ++blk) {
        const unsigned* q = pp + blk * NB2 + t * 4;
        h0 += q[0]; h1 += q[1]; h2 += q[2]; h3 += q[3];
    }
    csum[t] = h0 + h1 + h2 + h3;
    unsigned* sh = shist + (size_t)img * NB2;
    sh[t * 4] = h0; sh[t * 4 + 1] = h1; sh[t * 4 + 2] = h2; sh[t * 4 + 3] = h3;
    __syncthreads();
    // zero gbcur (same memory as parts; all reads done), ecnt, bcnt, bcur
    unsigned* gc = parts + (size_t)img * NB2 * 16;
    for (int i = t; i < NB2 * 16; i += 256) gc[i] = 0;
    if (t < GSTRIDE) ecnt[img * GSTRIDE + t] = 0;
    if (t < NXB) { bcnt[img * NXB + t] = 0; bcur[img * NXB + t] = 0; }
    if (t == 0) {
        unsigned a = 0;
        for (int g = 255; g >= 0; --g) { unsigned c = csum[g]; suf[g] = a; a += c; }
        unsigned acc = 0, before = 0;
        int c = -1;
        for (int cc = 255; cc >= 0; --cc) {
            if (acc + csum[cc] >= (unsigned)TOPK) { c = cc; before = acc; break; }
            acc += csum[cc];
        }
        unsigned cutb = B2BASE;
        if (c >= 0) {
            unsigned s2 = before;
            cutb = B2BASE + (unsigned)c * 4u;
            for (int b = c * 4 + 3; b >= c * 4; --b) {
                s2 += sh[b];
                if (s2 >= (unsigned)TOPK) { cutb = B2BASE + (unsigned)b; break; }
            }
        }
        cut[img] = cutb;
    }
    __syncthreads();
    unsigned a = suf[t];
    unsigned* sb = sbase + (size_t)img * NB2 + t * 4;
    sb[3] = a;
    sb[2] = a + h3;
    sb[1] = a + h3 + h2;
    sb[0] = a + h3 + h2 + h1;
}

// K3: gather candidates directly into their bucket segment (rank-scatter).
__global__ void __launch_bounds__(256) k_gather2(
        const float* __restrict__ conf, const unsigned* __restrict__ cut,
        const unsigned* __restrict__ sbase, unsigned* __restrict__ gbcur,
        unsigned long long* __restrict__ keys) {
    int q = blockIdx.x * 256 + threadIdx.x;
    int img = blockIdx.y;
    if (q >= HPNUM) return;
    unsigned cutb = cut[img];
    float4 v = ((const float4*)(conf + (size_t)img * PNUM * 2))[q];
    const unsigned* sb = sbase + (size_t)img * NB2;
    unsigned* gc = gbcur + (size_t)img * NB2 * 16;
    unsigned long long* kp = keys + (size_t)img * CAP;
    #pragma unroll
    for (int e = 0; e < 2; ++e) {
        float s = e ? v.w : v.y;
        if (s > 0.01f) {
            unsigned o = f2ord(s);
            if ((o >> 16) >= cutb) {
                unsigned wb = (o >> 16) - B2BASE;
                unsigned pos = sb[wb] + atomicAdd(&gc[wb * 16], 1u);
                if (pos < (unsigned)CAP)
                    kp[pos] = ((unsigned long long)o << 32)
                              | (unsigned)(~(unsigned)(2 * q + e));
            }
        }
    }
}

// K4: per-segment descending sort (<=1024 keys). One block per (bucket,img).
__global__ void __launch_bounds__(256) k_ssort(
        unsigned long long* __restrict__ keys, const unsigned* __restrict__ hist,
        const unsigned* __restrict__ cut, const unsigned* __restrict__ sbase) {
    int img = blockIdx.y;
    int b = blockIdx.x;
    if (B2BASE + (unsigned)b < cut[img]) return;
    unsigned cnt = hist[(size_t)img * NB2 + b];
    if (cnt <= 1) return;
    if (cnt > 1024) cnt = 1024;
    unsigned base = sbase[(size_t)img * NB2 + b];
    __shared__ unsigned long long sk[1024];
    unsigned long long* kp = keys + (size_t)img * CAP + base;
    int tid = threadIdx.x;
    for (int i = tid; i < 1024; i += 256) sk[i] = (i < (int)cnt) ? kp[i] : 0ull;
    __syncthreads();
    for (int k = 2; k <= 1024; k <<= 1) {
        for (int j = k >> 1; j > 0; j >>= 1) {
            for (int t = tid; t < 512; t += 256) {
                int i = ((t & ~(j - 1)) << 1) | (t & (j - 1));
                int p = i | j;
                bool desc = ((i & k) == 0);
                unsigned long long a = sk[i], bb = sk[p];
                bool sw = desc ? (a < bb) : (a > bb);
                if (sw) { sk[i] = bb; sk[p] = a; }
            }
            __syncthreads();
        }
    }
    for (int i = tid; i < (int)cnt; i += 256) kp[i] = sk[i];
}

// K5: decode sorted top-5000 keys -> SC + packed BOX4(x1,y1,x2,y2); also
// counts spatial buckets into global bcnt (wide, replaces k_bucket phase A).
__global__ void __launch_bounds__(256) k_decode(
        const unsigned long long* __restrict__ keys,
        const float* __restrict__ loc, const float* __restrict__ pri,
        float* __restrict__ SC, float4* __restrict__ BOX4,
        unsigned* __restrict__ bcnt) {
    int gidx = blockIdx.x * 256 + threadIdx.x;
    if (gidx >= BNUM * TOPK) return;
    int img = gidx / TOPK;
    int r = gidx - img * TOPK;
    unsigned long long key = keys[(size_t)img * CAP + r];
    size_t o = (size_t)img * TOPK + r;
    float s, x1, y1, x2, y2;
    if (key != 0ull) {
        unsigned ordv = (unsigned)(key >> 32);
        s = ord2f(ordv);
        unsigned p = ~(unsigned)(key & 0xFFFFFFFFull);
        const float* lp = loc + ((size_t)img * PNUM + p) * 4;
        const float* pp = pri + (size_t)p * 4;
        float lx = lp[0], ly = lp[1], lw = lp[2], lh = lp[3];
        float px = pp[0], py = pp[1], pw = pp[2], ph = pp[3];
        float cx = px + (lx * 0.1f) * pw;
        float cy = py + (ly * 0.1f) * ph;
        float w = pw * expf(lw * 0.2f);
        float h = ph * expf(lh * 0.2f);
        x1 = cx - w * 0.5f;
        y1 = cy - h * 0.5f;
        x2 = x1 + w;
        y2 = y1 + h;
    } else {
        s = -1.0f; x1 = 0.f; y1 = 0.f; x2 = 0.f; y2 = 0.f;
    }
    SC[o] = s;
    BOX4[o] = make_float4(x1, y1, x2, y2);
    atomicAdd(&bcnt[img * NXB + bucketOf(x1)], 1u);
}

// K6: wide bucket scatter. Each block redundantly prefixes the 128 counts
// (cheap) then scatters its 256 rows via global atomics. Intra-bucket order
// is arbitrary -- k_pair4's predicates emit each qualifying pair exactly
// once regardless, and the fixpoint keep-set is order-independent.
__global__ void __launch_bounds__(256) k_bscat(
        const unsigned* __restrict__ bcnt, unsigned* __restrict__ bcur,
        const float4* __restrict__ BOX4,
        unsigned* __restrict__ bofs, unsigned* __restrict__ sidx,
        float4* __restrict__ sbox) {
    __shared__ unsigned lc[NXB], bpre[NXB + 1];
    int img = blockIdx.y;
    int tid = threadIdx.x;
    if (tid < NXB) lc[tid] = bcnt[img * NXB + tid];
    __syncthreads();
    if (tid == 0) {
        unsigned a = 0;
        for (int b = 0; b < NXB; ++b) { bpre[b] = a; a += lc[b]; }
        bpre[NXB] = a;
    }
    __syncthreads();
    if (blockIdx.x == 0 && tid <= NXB) bofs[img * 130 + tid] = bpre[tid];
    int r = blockIdx.x * 256 + tid;
    if (r < TOPK) {
        float4 b = BOX4[(size_t)img * TOPK + r];
        int bk = bucketOf(b.x);
        unsigned s = bpre[bk] + atomicAdd(&bcur[img * NXB + bk], 1u);
        int base = img * BSTRIDE;
        sidx[base + s] = (unsigned)r;
        sbox[base + s] = b;
    }
}

// K7: 4-slot-per-wave bucketed pair search with packed float4 candidates and
// register double-buffer prefetch. Predicates keep the edge set identical to
// the per-box scan.
__global__ void __launch_bounds__(256) k_pair4(
        const unsigned* __restrict__ bofs, const unsigned* __restrict__ sidx,
        const float4* __restrict__ sbox,
        unsigned* __restrict__ ecnt, unsigned* __restrict__ edges) {
    __shared__ unsigned ebuf[EBUF];
    __shared__ unsigned ecl, ebase;
    int img = blockIdx.y;
    int wid = threadIdx.x >> 6;
    int lane = threadIdx.x & 63;
    int sb0 = (blockIdx.x * 4 + wid) * 4;         // first of 4 slots
    if (threadIdx.x == 0) ecl = 0;
    __syncthreads();
    unsigned* ec = ecnt + (size_t)img * GSTRIDE;
    unsigned* eg = edges + (size_t)img * CAPE;
    if (sb0 < TOPK) {
        int base = img * BSTRIDE;
        float x1k[4], x2k[4], y1k[4], y2k[4], ark[4];
        unsigned rk[4];
        bool act[4];
        #pragma unroll
        for (int k = 0; k < 4; ++k) {
            act[k] = (sb0 + k) < TOPK;
            int s = act[k] ? (sb0 + k) : sb0;
            float4 bk = sbox[base + s];
            x1k[k] = bk.x; y1k[k] = bk.y; x2k[k] = bk.z; y2k[k] = bk.w;
            ark[k] = (bk.z - bk.x) * (bk.w - bk.y);
            rk[k] = sidx[base + s];
        }
        int b1 = bucketOf(x1k[0]);                // min bucket (slot-monotone)
        int b2m = bucketOf(x2k[0]);
        #pragma unroll
        for (int k = 1; k < 4; ++k)
            if (act[k]) { int b = bucketOf(x2k[k]); if (b > b2m) b2m = b; }
        const unsigned* bo = bofs + img * 130;
        unsigned s0 = bo[b1], s1 = bo[b2m + 1];
        if (s0 < s1) {
            unsigned nit = (s1 - s0 + 63) >> 6;
            unsigned c0 = s0 + (unsigned)lane;
            if (c0 > s1 - 1) c0 = s1 - 1;         // clamp: always valid
            float4 cb = sbox[base + c0];
            unsigned cr = sidx[base + c0];
            for (unsigned it = 0; it < nit; ++it) {
                float4 nb = cb; unsigned nr = cr;
                if (it + 1 < nit) {               // uniform prefetch
                    unsigned cn = s0 + (it + 1) * 64 + (unsigned)lane;
                    if (cn > s1 - 1) cn = s1 - 1;
                    nb = sbox[base + cn];
                    nr = sidx[base + cn];
                }
                bool in = (s0 + it * 64 + (unsigned)lane) < s1;
                float bar = (cb.z - cb.x) * (cb.w - cb.y);
                #pragma unroll
                for (int k = 0; k < 4; ++k) {
                    bool hit = false;
                    unsigned edge = 0;
                    if (in && act[k] && cb.x >= x1k[k]
                        && !(cb.x == x1k[k] && cr <= rk[k])) {
                        float dx = fminf(x2k[k], cb.z) - fmaxf(x1k[k], cb.x);
                        if (dx > 0.0f) {
                            float dy = fminf(y2k[k], cb.w) - fmaxf(y1k[k], cb.y);
                            if (dy > 0.0f) {
                                float inter = dx * dy;
                                float iou = inter / (bar + ark[k] - inter);
                                if (iou > 0.3f) {
                                    unsigned su = (rk[k] < cr) ? rk[k] : cr;
                                    unsigned vi = (rk[k] < cr) ? cr : rk[k];
                                    edge = (vi << 13) | su;
                                    hit = true;
                                }
                            }
                        }
                    }
                    unsigned long long bal = __ballot(hit);
                    if (bal) {
                        int n = __popcll(bal);
                        unsigned wb = 0;
                        if (lane == 0) wb = atomicAdd(&ecl, (unsigned)n);
                        wb = __shfl(wb, 0, 64);
                        if (hit) {
                            unsigned long long lt =
                                (lane == 0) ? 0ull : ((1ull << lane) - 1ull);
                            unsigned p = wb + (unsigned)__popcll(bal & lt);
                            if (p < (unsigned)EBUF) ebuf[p] = edge;
                            else {
                                unsigned gp = atomicAdd(ec, 1u);
                                if (gp < (unsigned)CAPE) eg[gp] = edge;
                            }
                        }
                    }
                }
                cb = nb; cr = nr;
            }
        }
    }
    __syncthreads();
    unsigned n = min(ecl, (unsigned)EBUF);
    if (threadIdx.x == 0 && n) ebase = atomicAdd(ec, n);
    __syncthreads();
    for (unsigned i = threadIdx.x; i < n; i += 256) {
        unsigned p = ebase + i;
        if (p < (unsigned)CAPE) eg[p] = ebuf[i];
    }
}

// K8: edge-parallel monotone fixpoint NMS resolve + compaction.
__global__ void __launch_bounds__(256) k_nms3(
        const float* __restrict__ SC, const float4* __restrict__ BOX4,
        const unsigned* __restrict__ ecnt, const unsigned* __restrict__ edges,
        float* __restrict__ out) {
    __shared__ unsigned lgrp[ELDS];               // 40 KiB raw edge copy
    __shared__ unsigned undL[160], keptL[160], blockL[160];
    __shared__ unsigned pfx[80];
    __shared__ int chg[2];
    int img = blockIdx.x;
    int tid = threadIdx.x;
    int l = tid & 63;
    int wid = tid >> 6;
    size_t ib = (size_t)img * TOPK;
    const float* sc = SC + ib;

    if (tid < 160) { keptL[tid] = 0u; blockL[tid] = 0u; }
    if (tid < 2) chg[tid] = 0;
    // und init: valid = row in range and above conf threshold
    for (int w = wid; w < NWORDS; w += 4) {
        int row = w * 64 + l;
        bool valid = (row < TOPK) && (sc[row] > 0.01f);
        unsigned long long b = __ballot(valid);
        if (l == 0) {
            undL[2 * w]     = (unsigned)b;
            undL[2 * w + 1] = (unsigned)(b >> 32);
        }
    }
    unsigned E = min(ecnt[(size_t)img * GSTRIDE], (unsigned)CAPE);
    const unsigned* eimg = edges + (size_t)img * CAPE;
    bool inl = (E <= (unsigned)ELDS);             // uniform across block
    if (inl) for (unsigned e = tid; e < E; e += 256) lgrp[e] = eimg[e];
    __syncthreads();

    for (int round = 0; round < 256; ++round) {
        int par = round & 1;
        for (unsigned e = tid; e < E; e += 256) {
            unsigned ed = inl ? lgrp[e] : eimg[e];
            unsigned s = ed & 8191u;
            unsigned v = ed >> 13;
            unsigned sw = s >> 5, sb = s & 31u;
            unsigned vw = v >> 5, vb = 1u << (v & 31u);
            if ((keptL[sw] >> sb) & 1u) {
                if (undL[vw] & vb) {
                    unsigned old = atomicAnd(&undL[vw], ~vb);
                    if (old & vb) chg[par] = 1;   // a real kill happened
                }
            } else if ((undL[sw] >> sb) & 1u) {
                if (!(blockL[vw] & vb)) atomicOr(&blockL[vw], vb);
            }
        }
        __syncthreads();
        if (tid < NW32) {
            unsigned nk = undL[tid] & ~blockL[tid];
            if (nk) {
                keptL[tid] |= nk;
                undL[tid] &= ~nk;
                chg[par] = 1;
            }
            blockL[tid] = 0u;
        }
        if (tid == 0) chg[par ^ 1] = 0;           // pre-zero next round's flag
        __syncthreads();
        if (!chg[par]) break;                     // uniform
    }

    if (tid == 0) {
        unsigned acc = 0;
        for (int w = 0; w < NWORDS; ++w) {
            pfx[w] = acc;
            acc += (unsigned)(__popc(keptL[2 * w]) + __popc(keptL[2 * w + 1]));
        }
    }
    __syncthreads();
    const float4* bx = BOX4 + ib;
    float* op = out + (((size_t)img * 2) + 1) * TOPK * 5;
    for (int w = wid; w < NWORDS; w += 4) {
        unsigned long long kw =
            ((unsigned long long)keptL[2 * w + 1] << 32) | keptL[2 * w];
        if (!kw) continue;
        int row = w * 64 + l;
        if ((kw >> l) & 1ull) {
            int rank = (int)pfx[w] + (int)__popcll(kw & ((1ull << l) - 1ull));
            float4 b = bx[row];
            float* r = op + (size_t)rank * 5;
            r[0] = sc[row]; r[1] = b.x; r[2] = b.y; r[3] = b.z; r[4] = b.w;
        }
    }
}

extern "C" void kernel_launch(void* const* d_in, const int* in_sizes, int n_in,
                              void* d_out, int out_size, void* d_ws, size_t ws_size,
                              hipStream_t stream) {
    (void)in_sizes; (void)n_in; (void)ws_size;
    const float* loc  = (const float*)d_in[0];   // (16, 136500, 4)
    const float* conf = (const float*)d_in[1];   // (16*136500, 2)
    const float* pri  = (const float*)d_in[2];   // (136500, 4)
    float* out = (float*)d_out;                  // (16, 2, 5000, 5)
    char* ws = (char*)d_ws;

    float* SC   = (float*)(ws + OFF_SC);
    float4* BOX4 = (float4*)(ws + OFF_BOX4);
    unsigned* shist = (unsigned*)(ws + OFF_HIST);
    unsigned* cut  = (unsigned*)(ws + OFF_CUT);
    unsigned* sbase = (unsigned*)(ws + OFF_SBASE);
    unsigned* gbcur = (unsigned*)(ws + OFF_GBCUR);   // parts, then counters
    unsigned long long* keys = (unsigned long long*)(ws + OFF_KEYS);
    unsigned* ecnt = (unsigned*)(ws + OFF_ECNT);
    unsigned* bcnt = (unsigned*)(ws + OFF_BCNT);
    unsigned* bcur = (unsigned*)(ws + OFF_BCUR);
    unsigned* edges = (unsigned*)(ws + OFF_EDGE);
    unsigned* bofs = (unsigned*)(ws + OFF_BOFS);
    unsigned* sidx = (unsigned*)(ws + OFF_SIDX);
    float4* sbox = (float4*)(ws + OFF_SBOX);

    hipMemsetAsync(d_out, 0, (size_t)out_size * sizeof(float), stream);

    dim3 gh1(NHB, BNUM);                         // 16 partial-hist blocks/image
    k_hist<<<gh1, 256, 0, stream>>>(conf, gbcur);
    k_cutoff2<<<BNUM, 256, 0, stream>>>(gbcur, shist, cut, sbase,
                                        ecnt, bcnt, bcur);
    dim3 gh2((HPNUM + 255) / 256, BNUM);
    k_gather2<<<gh2, 256, 0, stream>>>(conf, cut, sbase, gbcur, keys);
    dim3 gs(NB2, BNUM);                          // per-segment sorts
    k_ssort<<<gs, 256, 0, stream>>>(keys, shist, cut, sbase);
    k_decode<<<(BNUM * TOPK + 255) / 256, 256, 0, stream>>>(
        keys, loc, pri, SC, BOX4, bcnt);
    dim3 gb((TOPK + 255) / 256, BNUM);           // wide bucket scatter
    k_bscat<<<gb, 256, 0, stream>>>(bcnt, bcur, BOX4, bofs, sidx, sbox);
    dim3 pg((TOPK + 15) / 16, BNUM);             // 4 waves x 4 slots per block
    k_pair4<<<pg, 256, 0, stream>>>(bofs, sidx, sbox, ecnt, edges);
    k_nms3<<<BNUM, 256, 0, stream>>>(SC, BOX4, ecnt, edges, out);
}

// Round 5
// 242.224 us; speedup vs baseline: 1.0395x; 1.0395x over previous
//
#include <hip/hip_runtime.h>
#include <math.h>

#pragma clang fp contract(off)

// Problem constants (match reference)
#define PNUM 136500      // sum of f*f
#define HPNUM 68250      // PNUM/2 (exact)
#define BNUM 16
#define TOPK 5000
#define CAP 8192         // candidate capacity per image
#define NB2 1024         // histogram window buckets (covers ord16 of (0.01, 1.0))
#define B2BASE 0xBC00u   // window base: f2ord(0.01)>>16 = 0xBC23 >= 0xBC00
#define NWORDS 79        // ceil(5000/64)
#define NW32 158         // 32-bit state words per image (NWORDS*2)
#define GSTRIDE 32       // ecnt padding: 32 u32 = 128 B per image
#define CAPE 65536       // edge capacity per image (expected E ~ 1-3k)
#define ELDS 10240       // LDS edge-copy capacity (global fallback beyond)
#define NXB 128          // spatial x1 buckets
#define BSTRIDE 5120     // per-image bucket-array stride (>= TOPK)
#define EBUF 3072        // per-block LDS edge buffer

// Workspace layout (bytes).
#define OFF_SC    ((size_t)0)                 // 320,000
#define OFF_BOX4  (OFF_SC + 320000)           // 16*5000*16 = 1,280,000
#define OFF_HIST  ((size_t)1920000)           // 16*1024*4 = 65,536
#define OFF_CUT   (OFF_HIST + 65536)          // 64
#define OFF_SBASE (OFF_CUT + 64)              // 65,536
#define OFF_GBCUR (OFF_SBASE + 65536)         // 16*1024*64 = 1,048,576
#define OFF_KEYS  (OFF_GBCUR + 1048576)       // 16*8192*8 = 1,048,576
#define OFF_ECNT  (OFF_KEYS + 1048576)        // 2,048
#define OFF_BCNT  (OFF_ECNT + 2048)           // 16*128*4 = 8,192
#define OFF_BCUR  (OFF_BCNT + 8192)           // 8,192
#define OFF_ZEND  (OFF_BCUR + 8192)           // memset range end
#define OFF_EDGE  (OFF_ZEND)                  // 16*65536*4 = 4,194,304
#define OFF_GRP   (OFF_EDGE + 4194304)        // overlay region for bucket arrays
#define OFF_BOFS  (OFF_GRP)                   // 16*130*4 (pad to 16384)
#define OFF_SIDX  (OFF_GRP + 16384)           // u32 [16*5120]
#define OFF_SBOX  (OFF_SIDX + 327680)         // float4 [16*5120] = 1,310,720

__device__ __forceinline__ unsigned f2ord(float f) {
    unsigned u = __float_as_uint(f);
    return (u & 0x80000000u) ? ~u : (u | 0x80000000u);
}
__device__ __forceinline__ float ord2f(unsigned o) {
    unsigned u = (o & 0x80000000u) ? (o ^ 0x80000000u) : ~o;
    return __uint_as_float(u);
}
// monotone x1 -> bucket map; identical in k_decode, k_bscat, k_pair4
__device__ __forceinline__ int bucketOf(float x) {
    int b = (int)((x + 0.6f) * 71.111115f);   // 128 buckets over [-0.6, 1.2]
    return (b < 0) ? 0 : ((b > 127) ? 127 : b);
}

// K1: per-image histogram over the 1024-bucket window in LDS + atomic merge.
// (round-3 form: wide 256-block merge beats a 16-block reduce kernel)
__global__ void __launch_bounds__(256) k_hist(const float* __restrict__ conf,
                                              unsigned* __restrict__ hist) {
    __shared__ unsigned lh[NB2];
    int img = blockIdx.y;
    for (int i = threadIdx.x; i < NB2; i += 256) lh[i] = 0;
    __syncthreads();
    const float4* src = (const float4*)(conf + (size_t)img * PNUM * 2);
    int stride = gridDim.x * 256;
    for (int q = blockIdx.x * 256 + threadIdx.x; q < HPNUM; q += stride) {
        float4 v = src[q];
        if (v.y > 0.01f) atomicAdd(&lh[(f2ord(v.y) >> 16) - B2BASE], 1u);
        if (v.w > 0.01f) atomicAdd(&lh[(f2ord(v.w) >> 16) - B2BASE], 1u);
    }
    __syncthreads();
    unsigned* h = hist + (size_t)img * NB2;
    for (int i = threadIdx.x; i < NB2; i += 256) {
        unsigned c = lh[i];
        if (c) atomicAdd(&h[i], c);
    }
}

// K2: cutoff + per-bucket suffix base ranks (round-3 form).
__global__ void __launch_bounds__(256) k_cutoff2(const unsigned* __restrict__ hist,
                                                 unsigned* __restrict__ cut,
                                                 unsigned* __restrict__ sbase) {
    __shared__ unsigned csum[256], suf[256];
    int img = blockIdx.x;
    int t = threadIdx.x;
    const unsigned* h = hist + (size_t)img * NB2;
    unsigned h0 = h[t * 4], h1 = h[t * 4 + 1], h2 = h[t * 4 + 2], h3 = h[t * 4 + 3];
    csum[t] = h0 + h1 + h2 + h3;
    __syncthreads();
    if (t == 0) {
        unsigned a = 0;
        for (int g = 255; g >= 0; --g) { unsigned c = csum[g]; suf[g] = a; a += c; }
        unsigned acc = 0, before = 0;
        int c = -1;
        for (int cc = 255; cc >= 0; --cc) {
            if (acc + csum[cc] >= (unsigned)TOPK) { c = cc; before = acc; break; }
            acc += csum[cc];
        }
        unsigned cutb = B2BASE;
        if (c >= 0) {
            unsigned s2 = before;
            cutb = B2BASE + (unsigned)c * 4u;
            for (int b = c * 4 + 3; b >= c * 4; --b) {
                s2 += h[b];
                if (s2 >= (unsigned)TOPK) { cutb = B2BASE + (unsigned)b; break; }
            }
        }
        cut[img] = cutb;
    }
    __syncthreads();
    unsigned a = suf[t];
    unsigned* sb = sbase + (size_t)img * NB2 + t * 4;
    sb[3] = a;
    sb[2] = a + h3;
    sb[1] = a + h3 + h2;
    sb[0] = a + h3 + h2 + h1;
}

// K3: gather candidates directly into their bucket segment (rank-scatter).
__global__ void __launch_bounds__(256) k_gather2(
        const float* __restrict__ conf, const unsigned* __restrict__ cut,
        const unsigned* __restrict__ sbase, unsigned* __restrict__ gbcur,
        unsigned long long* __restrict__ keys) {
    int q = blockIdx.x * 256 + threadIdx.x;
    int img = blockIdx.y;
    if (q >= HPNUM) return;
    unsigned cutb = cut[img];
    float4 v = ((const float4*)(conf + (size_t)img * PNUM * 2))[q];
    const unsigned* sb = sbase + (size_t)img * NB2;
    unsigned* gc = gbcur + (size_t)img * NB2 * 16;
    unsigned long long* kp = keys + (size_t)img * CAP;
    #pragma unroll
    for (int e = 0; e < 2; ++e) {
        float s = e ? v.w : v.y;
        if (s > 0.01f) {
            unsigned o = f2ord(s);
            if ((o >> 16) >= cutb) {
                unsigned wb = (o >> 16) - B2BASE;
                unsigned pos = sb[wb] + atomicAdd(&gc[wb * 16], 1u);
                if (pos < (unsigned)CAP)
                    kp[pos] = ((unsigned long long)o << 32)
                              | (unsigned)(~(unsigned)(2 * q + e));
            }
        }
    }
}

// K4: per-segment descending sort (<=1024 keys). One block per (bucket,img).
__global__ void __launch_bounds__(256) k_ssort(
        unsigned long long* __restrict__ keys, const unsigned* __restrict__ hist,
        const unsigned* __restrict__ cut, const unsigned* __restrict__ sbase) {
    int img = blockIdx.y;
    int b = blockIdx.x;
    if (B2BASE + (unsigned)b < cut[img]) return;
    unsigned cnt = hist[(size_t)img * NB2 + b];
    if (cnt <= 1) return;
    if (cnt > 1024) cnt = 1024;
    unsigned base = sbase[(size_t)img * NB2 + b];
    __shared__ unsigned long long sk[1024];
    unsigned long long* kp = keys + (size_t)img * CAP + base;
    int tid = threadIdx.x;
    for (int i = tid; i < 1024; i += 256) sk[i] = (i < (int)cnt) ? kp[i] : 0ull;
    __syncthreads();
    for (int k = 2; k <= 1024; k <<= 1) {
        for (int j = k >> 1; j > 0; j >>= 1) {
            for (int t = tid; t < 512; t += 256) {
                int i = ((t & ~(j - 1)) << 1) | (t & (j - 1));
                int p = i | j;
                bool desc = ((i & k) == 0);
                unsigned long long a = sk[i], bb = sk[p];
                bool sw = desc ? (a < bb) : (a > bb);
                if (sw) { sk[i] = bb; sk[p] = a; }
            }
            __syncthreads();
        }
    }
    for (int i = tid; i < (int)cnt; i += 256) kp[i] = sk[i];
}

// K5: decode sorted top-5000 keys -> SC + packed BOX4(x1,y1,x2,y2); also
// counts spatial buckets via per-block LDS histogram (a block can span at
// most 2 images since 256 < TOPK). No early return: barrier-safe.
__global__ void __launch_bounds__(256) k_decode(
        const unsigned long long* __restrict__ keys,
        const float* __restrict__ loc, const float* __restrict__ pri,
        float* __restrict__ SC, float4* __restrict__ BOX4,
        unsigned* __restrict__ bcnt) {
    __shared__ unsigned lb[2][NXB];
    int tid = threadIdx.x;
    if (tid < NXB) { lb[0][tid] = 0; lb[1][tid] = 0; }
    __syncthreads();
    int gidx = blockIdx.x * 256 + tid;
    int img0 = (blockIdx.x * 256) / TOPK;
    bool ok = gidx < BNUM * TOPK;
    if (ok) {
        int img = gidx / TOPK;
        int r = gidx - img * TOPK;
        unsigned long long key = keys[(size_t)img * CAP + r];
        size_t o = (size_t)img * TOPK + r;
        float s, x1, y1, x2, y2;
        if (key != 0ull) {
            unsigned ordv = (unsigned)(key >> 32);
            s = ord2f(ordv);
            unsigned p = ~(unsigned)(key & 0xFFFFFFFFull);
            const float* lp = loc + ((size_t)img * PNUM + p) * 4;
            const float* pp = pri + (size_t)p * 4;
            float lx = lp[0], ly = lp[1], lw = lp[2], lh = lp[3];
            float px = pp[0], py = pp[1], pw = pp[2], ph = pp[3];
            float cx = px + (lx * 0.1f) * pw;
            float cy = py + (ly * 0.1f) * ph;
            float w = pw * expf(lw * 0.2f);
            float h = ph * expf(lh * 0.2f);
            x1 = cx - w * 0.5f;
            y1 = cy - h * 0.5f;
            x2 = x1 + w;
            y2 = y1 + h;
        } else {
            s = -1.0f; x1 = 0.f; y1 = 0.f; x2 = 0.f; y2 = 0.f;
        }
        SC[o] = s;
        BOX4[o] = make_float4(x1, y1, x2, y2);
        atomicAdd(&lb[img - img0][bucketOf(x1)], 1u);
    }
    __syncthreads();
    if (tid < 2 * NXB) {
        int sub = tid >> 7;               // 0 or 1
        int bk = tid & (NXB - 1);
        int img = img0 + sub;
        unsigned c = lb[sub][bk];
        if (c && img < BNUM) atomicAdd(&bcnt[img * NXB + bk], c);
    }
}

// K6: wide bucket scatter. Each block redundantly prefixes the 128 counts
// (cheap) then scatters its 256 rows via global atomics. Intra-bucket order
// is arbitrary -- k_pair4's predicates emit each qualifying pair exactly
// once regardless, and the fixpoint keep-set is order-independent.
__global__ void __launch_bounds__(256) k_bscat(
        const unsigned* __restrict__ bcnt, unsigned* __restrict__ bcur,
        const float4* __restrict__ BOX4,
        unsigned* __restrict__ bofs, unsigned* __restrict__ sidx,
        float4* __restrict__ sbox) {
    __shared__ unsigned lc[NXB], bpre[NXB + 1];
    int img = blockIdx.y;
    int tid = threadIdx.x;
    if (tid < NXB) lc[tid] = bcnt[img * NXB + tid];
    __syncthreads();
    if (tid == 0) {
        unsigned a = 0;
        for (int b = 0; b < NXB; ++b) { bpre[b] = a; a += lc[b]; }
        bpre[NXB] = a;
    }
    __syncthreads();
    if (blockIdx.x == 0 && tid <= NXB) bofs[img * 130 + tid] = bpre[tid];
    int r = blockIdx.x * 256 + tid;
    if (r < TOPK) {
        float4 b = BOX4[(size_t)img * TOPK + r];
        int bk = bucketOf(b.x);
        unsigned s = bpre[bk] + atomicAdd(&bcur[img * NXB + bk], 1u);
        int base = img * BSTRIDE;
        sidx[base + s] = (unsigned)r;
        sbox[base + s] = b;
    }
}

// K7: 4-slot-per-wave bucketed pair search with packed float4 candidates and
// register double-buffer prefetch. Predicates keep the edge set identical to
// the per-box scan.
__global__ void __launch_bounds__(256) k_pair4(
        const unsigned* __restrict__ bofs, const unsigned* __restrict__ sidx,
        const float4* __restrict__ sbox,
        unsigned* __restrict__ ecnt, unsigned* __restrict__ edges) {
    __shared__ unsigned ebuf[EBUF];
    __shared__ unsigned ecl, ebase;
    int img = blockIdx.y;
    int wid = threadIdx.x >> 6;
    int lane = threadIdx.x & 63;
    int sb0 = (blockIdx.x * 4 + wid) * 4;         // first of 4 slots
    if (threadIdx.x == 0) ecl = 0;
    __syncthreads();
    unsigned* ec = ecnt + (size_t)img * GSTRIDE;
    unsigned* eg = edges + (size_t)img * CAPE;
    if (sb0 < TOPK) {
        int base = img * BSTRIDE;
        float x1k[4], x2k[4], y1k[4], y2k[4], ark[4];
        unsigned rk[4];
        bool act[4];
        #pragma unroll
        for (int k = 0; k < 4; ++k) {
            act[k] = (sb0 + k) < TOPK;
            int s = act[k] ? (sb0 + k) : sb0;
            float4 bk = sbox[base + s];
            x1k[k] = bk.x; y1k[k] = bk.y; x2k[k] = bk.z; y2k[k] = bk.w;
            ark[k] = (bk.z - bk.x) * (bk.w - bk.y);
            rk[k] = sidx[base + s];
        }
        int b1 = bucketOf(x1k[0]);                // min bucket (slot-monotone)
        int b2m = bucketOf(x2k[0]);
        #pragma unroll
        for (int k = 1; k < 4; ++k)
            if (act[k]) { int b = bucketOf(x2k[k]); if (b > b2m) b2m = b; }
        const unsigned* bo = bofs + img * 130;
        unsigned s0 = bo[b1], s1 = bo[b2m + 1];
        if (s0 < s1) {
            unsigned nit = (s1 - s0 + 63) >> 6;
            unsigned c0 = s0 + (unsigned)lane;
            if (c0 > s1 - 1) c0 = s1 - 1;         // clamp: always valid
            float4 cb = sbox[base + c0];
            unsigned cr = sidx[base + c0];
            for (unsigned it = 0; it < nit; ++it) {
                float4 nb = cb; unsigned nr = cr;
                if (it + 1 < nit) {               // uniform prefetch
                    unsigned cn = s0 + (it + 1) * 64 + (unsigned)lane;
                    if (cn > s1 - 1) cn = s1 - 1;
                    nb = sbox[base + cn];
                    nr = sidx[base + cn];
                }
                bool in = (s0 + it * 64 + (unsigned)lane) < s1;
                float bar = (cb.z - cb.x) * (cb.w - cb.y);
                #pragma unroll
                for (int k = 0; k < 4; ++k) {
                    bool hit = false;
                    unsigned edge = 0;
                    if (in && act[k] && cb.x >= x1k[k]
                        && !(cb.x == x1k[k] && cr <= rk[k])) {
                        float dx = fminf(x2k[k], cb.z) - fmaxf(x1k[k], cb.x);
                        if (dx > 0.0f) {
                            float dy = fminf(y2k[k], cb.w) - fmaxf(y1k[k], cb.y);
                            if (dy > 0.0f) {
                                float inter = dx * dy;
                                float iou = inter / (bar + ark[k] - inter);
                                if (iou > 0.3f) {
                                    unsigned su = (rk[k] < cr) ? rk[k] : cr;
                                    unsigned vi = (rk[k] < cr) ? cr : rk[k];
                                    edge = (vi << 13) | su;
                                    hit = true;
                                }
                            }
                        }
                    }
                    unsigned long long bal = __ballot(hit);
                    if (bal) {
                        int n = __popcll(bal);
                        unsigned wb = 0;
                        if (lane == 0) wb = atomicAdd(&ecl, (unsigned)n);
                        wb = __shfl(wb, 0, 64);
                        if (hit) {
                            unsigned long long lt =
                                (lane == 0) ? 0ull : ((1ull << lane) - 1ull);
                            unsigned p = wb + (unsigned)__popcll(bal & lt);
                            if (p < (unsigned)EBUF) ebuf[p] = edge;
                            else {
                                unsigned gp = atomicAdd(ec, 1u);
                                if (gp < (unsigned)CAPE) eg[gp] = edge;
                            }
                        }
                    }
                }
                cb = nb; cr = nr;
            }
        }
    }
    __syncthreads();
    unsigned n = min(ecl, (unsigned)EBUF);
    if (threadIdx.x == 0 && n) ebase = atomicAdd(ec, n);
    __syncthreads();
    for (unsigned i = threadIdx.x; i < n; i += 256) {
        unsigned p = ebase + i;
        if (p < (unsigned)CAPE) eg[p] = ebuf[i];
    }
}

// K8: edge-parallel monotone fixpoint NMS resolve + compaction.
__global__ void __launch_bounds__(256) k_nms3(
        const float* __restrict__ SC, const float4* __restrict__ BOX4,
        const unsigned* __restrict__ ecnt, const unsigned* __restrict__ edges,
        float* __restrict__ out) {
    __shared__ unsigned lgrp[ELDS];               // 40 KiB raw edge copy
    __shared__ unsigned undL[160], keptL[160], blockL[160];
    __shared__ unsigned pfx[80];
    __shared__ int chg[2];
    int img = blockIdx.x;
    int tid = threadIdx.x;
    int l = tid & 63;
    int wid = tid >> 6;
    size_t ib = (size_t)img * TOPK;
    const float* sc = SC + ib;

    if (tid < 160) { keptL[tid] = 0u; blockL[tid] = 0u; }
    if (tid < 2) chg[tid] = 0;
    // und init: valid = row in range and above conf threshold
    for (int w = wid; w < NWORDS; w += 4) {
        int row = w * 64 + l;
        bool valid = (row < TOPK) && (sc[row] > 0.01f);
        unsigned long long b = __ballot(valid);
        if (l == 0) {
            undL[2 * w]     = (unsigned)b;
            undL[2 * w + 1] = (unsigned)(b >> 32);
        }
    }
    unsigned E = min(ecnt[(size_t)img * GSTRIDE], (unsigned)CAPE);
    const unsigned* eimg = edges + (size_t)img * CAPE;
    bool inl = (E <= (unsigned)ELDS);             // uniform across block
    if (inl) for (unsigned e = tid; e < E; e += 256) lgrp[e] = eimg[e];
    __syncthreads();

    for (int round = 0; round < 256; ++round) {
        int par = round & 1;
        for (unsigned e = tid; e < E; e += 256) {
            unsigned ed = inl ? lgrp[e] : eimg[e];
            unsigned s = ed & 8191u;
            unsigned v = ed >> 13;
            unsigned sw = s >> 5, sb = s & 31u;
            unsigned vw = v >> 5, vb = 1u << (v & 31u);
            if ((keptL[sw] >> sb) & 1u) {
                if (undL[vw] & vb) {
                    unsigned old = atomicAnd(&undL[vw], ~vb);
                    if (old & vb) chg[par] = 1;   // a real kill happened
                }
            } else if ((undL[sw] >> sb) & 1u) {
                if (!(blockL[vw] & vb)) atomicOr(&blockL[vw], vb);
            }
        }
        __syncthreads();
        if (tid < NW32) {
            unsigned nk = undL[tid] & ~blockL[tid];
            if (nk) {
                keptL[tid] |= nk;
                undL[tid] &= ~nk;
                chg[par] = 1;
            }
            blockL[tid] = 0u;
        }
        if (tid == 0) chg[par ^ 1] = 0;           // pre-zero next round's flag
        __syncthreads();
        if (!chg[par]) break;                     // uniform
    }

    if (tid == 0) {
        unsigned acc = 0;
        for (int w = 0; w < NWORDS; ++w) {
            pfx[w] = acc;
            acc += (unsigned)(__popc(keptL[2 * w]) + __popc(keptL[2 * w + 1]));
        }
    }
    __syncthreads();
    const float4* bx = BOX4 + ib;
    float* op = out + (((size_t)img * 2) + 1) * TOPK * 5;
    for (int w = wid; w < NWORDS; w += 4) {
        unsigned long long kw =
            ((unsigned long long)keptL[2 * w + 1] << 32) | keptL[2 * w];
        if (!kw) continue;
        int row = w * 64 + l;
        if ((kw >> l) & 1ull) {
            int rank = (int)pfx[w] + (int)__popcll(kw & ((1ull << l) - 1ull));
            float4 b = bx[row];
            float* r = op + (size_t)rank * 5;
            r[0] = sc[row]; r[1] = b.x; r[2] = b.y; r[3] = b.z; r[4] = b.w;
        }
    }
}

extern "C" void kernel_launch(void* const* d_in, const int* in_sizes, int n_in,
                              void* d_out, int out_size, void* d_ws, size_t ws_size,
                              hipStream_t stream) {
    (void)in_sizes; (void)n_in; (void)ws_size;
    const float* loc  = (const float*)d_in[0];   // (16, 136500, 4)
    const float* conf = (const float*)d_in[1];   // (16*136500, 2)
    const float* pri  = (const float*)d_in[2];   // (136500, 4)
    float* out = (float*)d_out;                  // (16, 2, 5000, 5)
    char* ws = (char*)d_ws;

    float* SC   = (float*)(ws + OFF_SC);
    float4* BOX4 = (float4*)(ws + OFF_BOX4);
    unsigned* hist = (unsigned*)(ws + OFF_HIST);
    unsigned* cut  = (unsigned*)(ws + OFF_CUT);
    unsigned* sbase = (unsigned*)(ws + OFF_SBASE);
    unsigned* gbcur = (unsigned*)(ws + OFF_GBCUR);
    unsigned long long* keys = (unsigned long long*)(ws + OFF_KEYS);
    unsigned* ecnt = (unsigned*)(ws + OFF_ECNT);
    unsigned* bcnt = (unsigned*)(ws + OFF_BCNT);
    unsigned* bcur = (unsigned*)(ws + OFF_BCUR);
    unsigned* edges = (unsigned*)(ws + OFF_EDGE);
    unsigned* bofs = (unsigned*)(ws + OFF_BOFS);
    unsigned* sidx = (unsigned*)(ws + OFF_SIDX);
    float4* sbox = (float4*)(ws + OFF_SBOX);

    hipMemsetAsync(d_out, 0, (size_t)out_size * sizeof(float), stream);
    hipMemsetAsync(ws + OFF_HIST, 0, OFF_ZEND - OFF_HIST, stream);

    dim3 gh1(16, BNUM);                          // 16 grid-stride blocks/image
    k_hist<<<gh1, 256, 0, stream>>>(conf, hist);
    k_cutoff2<<<BNUM, 256, 0, stream>>>(hist, cut, sbase);
    dim3 gh2((HPNUM + 255) / 256, BNUM);
    k_gather2<<<gh2, 256, 0, stream>>>(conf, cut, sbase, gbcur, keys);
    dim3 gs(NB2, BNUM);                          // per-segment sorts
    k_ssort<<<gs, 256, 0, stream>>>(keys, hist, cut, sbase);
    k_decode<<<(BNUM * TOPK + 255) / 256, 256, 0, stream>>>(
        keys, loc, pri, SC, BOX4, bcnt);
    dim3 gb((TOPK + 255) / 256, BNUM);           // wide bucket scatter
    k_bscat<<<gb, 256, 0, stream>>>(bcnt, bcur, BOX4, bofs, sidx, sbox);
    dim3 pg((TOPK + 15) / 16, BNUM);             // 4 waves x 4 slots per block
    k_pair4<<<pg, 256, 0, stream>>>(bofs, sidx, sbox, ecnt, edges);
    k_nms3<<<BNUM, 256, 0, stream>>>(SC, BOX4, ecnt, edges, out);
}